// Round 6
// baseline (11685.722 us; speedup 1.0000x reference)
//
#include <hip/hip_runtime.h>
#include <hip/hip_bf16.h>
#include <hip/hip_fp16.h>

#define Bn 256
#define Sn 1024
#define Hn 256
#define Vn 128
#define En 128

typedef _Float16 f16x8 __attribute__((ext_vector_type(8)));
typedef _Float16 f16x4 __attribute__((ext_vector_type(4)));
typedef _Float16 f16x2 __attribute__((ext_vector_type(2)));
typedef float f32x4 __attribute__((ext_vector_type(4)));
typedef unsigned long long u64;

// column permutation: n = 64q + 16cb + c  ->  k' = 64q + 4c + cb
__device__ __forceinline__ int perm(int n) {
  return (n & 0xC0) | ((n & 15) << 2) | ((n >> 4) & 3);
}
__device__ __forceinline__ int iperm(int k) {
  return (k & 0xC0) | ((k & 3) << 4) | ((k >> 2) & 15);
}
// A-tile swizzle (row = byte>>9): XOR (row&7) into 16B-granule index
__device__ __forceinline__ int aswz(int b) { return b ^ (((b >> 9) & 7) << 4); }

__device__ __forceinline__ float tanh_fast(float z) {
  float e2 = __builtin_amdgcn_exp2f(z * 2.885390081777927f);
  return fmaf(-2.f, __builtin_amdgcn_rcpf(e2 + 1.f), 1.f);
}

#define BAR() asm volatile("s_waitcnt lgkmcnt(0)\n\ts_barrier" ::: "memory")

// ---------- prep: T2g[v][perm(h)] = f16(emb[v]·W_ih[h] + b_ih[h] + b_hh[h]);
//                  Wp[v][k'] = f16(W_ho[v][iperm(k')])
__global__ void k_prep(const float* __restrict__ emb, const float* __restrict__ W_ih,
                       const float* __restrict__ b_ih, const float* __restrict__ b_hh,
                       const float* __restrict__ W_ho,
                       _Float16* __restrict__ T2g, _Float16* __restrict__ Wp) {
  int bid = blockIdx.x, tid = threadIdx.x;
  if (bid < Vn) {
    int vv = bid, h = tid;
    const float4* e4 = (const float4*)(emb + vv * En);
    const float4* w4 = (const float4*)(W_ih + h * En);
    float acc = 0.f;
    #pragma unroll
    for (int i = 0; i < En / 4; ++i) {
      float4 a = e4[i], b = w4[i];
      acc += a.x * b.x + a.y * b.y + a.z * b.z + a.w * b.w;
    }
    T2g[vv * Hn + perm(h)] = (_Float16)(acc + b_ih[h] + b_hh[h]);
  } else if (Wp) {
    int vv = bid - Vn, kp = tid;
    Wp[vv * Hn + kp] = (_Float16)W_ho[vv * Hn + iperm(kp)];
  }
}

// ---------- recurrence: 16 blocks x 512 thr (8 waves, 2/SIMD).
// Wave (cq = w>>1, kh = w&1): col-quarter cq (cols 64cq..+64), k-half kh.
// Per step: 4 A-frag b128 reads (own k-half), 16 MFMAs, f16-packed partial
// exchange with SIMD-partner (w^1) via one b128 LDS slot, tanh over 8 elems,
// b32 h-write + global export. Two lgkm-only barriers per step.
__global__ __launch_bounds__(512, 1) void k_rnn(const int* __restrict__ inp,
    const float* __restrict__ hidden, const float* __restrict__ W_hh,
    const _Float16* __restrict__ T2g, float* out_base) {
  __shared__ _Float16 Abuf[2 * 16 * Hn];     // 16 KB  [m][k'] swizzled, dbuf
  __shared__ _Float16 Ppart[8 * 512];        // 8 KB   [wave][lane-slot 16B]
  __shared__ unsigned char idxb[Sn * 16];    // 16 KB  [t][m]

  const int tid = threadIdx.x;
  const int l = tid & 63;
  const int w = tid >> 6;      // 0..7
  const int cq = w >> 1;       // col quarter
  const int kh = w & 1;        // k half
  const int g = l >> 4;        // 0..3
  const int c = l & 15;
  const int bb0 = blockIdx.x << 4;

  // ---- stage idx bytes (V=128 fits u8)
  #pragma unroll
  for (int i = 0; i < 8; ++i) {
    int gi = tid + (i << 9);           // 0..4095
    int m = gi >> 8;                   // row 0..15
    int j = gi & 255;                  // int4 index
    int4 d = ((const int4*)(inp + (size_t)(bb0 + m) * Sn))[j];
    int t0 = j << 2;
    idxb[(t0 + 0) * 16 + m] = (unsigned char)d.x;
    idxb[(t0 + 1) * 16 + m] = (unsigned char)d.y;
    idxb[(t0 + 2) * 16 + m] = (unsigned char)d.z;
    idxb[(t0 + 3) * 16 + m] = (unsigned char)d.w;
  }

  // ---- W_hh B-frags: Bf[cb][ki] elem j = W_hh[64cq+16cb+c][iperm(32(4kh+ki)+8g+j)]
  f16x8 Bf[4][4];
  #pragma unroll
  for (int cb = 0; cb < 4; ++cb) {
    const float* wrow = W_hh + ((cq << 6) + (cb << 4) + c) * Hn;
    #pragma unroll
    for (int ki = 0; ki < 4; ++ki) {
      int ks = (kh << 2) + ki;
      union { _Float16 h[8]; f16x8 v8; } u;
      #pragma unroll
      for (int j = 0; j < 8; ++j)
        u.h[j] = (_Float16)wrow[iperm((ks << 5) + (g << 3) + j)];
      Bf[cb][ki] = u.v8;
    }
  }

  // per-thread LDS byte offsets (loop-invariant)
  const int xoff = (cq << 7) + (c << 3) + (kh << 2);  // byte off within 512B row
  int awr[4];
  #pragma unroll
  for (int r = 0; r < 4; ++r) awr[r] = aswz((((g << 2) + r) << 9) + xoff);
  int ard[4];
  #pragma unroll
  for (int ki = 0; ki < 4; ++ki)
    ard[ki] = aswz((c << 9) + (((kh << 2) + ki) << 6) + (g << 4));
  const int pslot = ((c << 6) + (g << 4)) ^ ((c & 7) << 4);
  const int pown = (w << 10) + pslot;
  const int ppar = ((w ^ 1) << 10) + pslot;

  const int cbf0 = kh << 1;            // finalized col-chunks
  const int cbo0 = (kh ^ 1) << 1;      // exchanged col-chunks

  // ---- initial h -> Abuf buffer 0 (each wave fills its own slots)
  #pragma unroll
  for (int r = 0; r < 4; ++r) {
    int m = (g << 2) + r;
    int n0 = (cq << 6) + (cbf0 << 4) + c;
    f16x2 hp;
    hp[0] = (_Float16)hidden[(bb0 + m) * Hn + n0];
    hp[1] = (_Float16)hidden[(bb0 + m) * Hn + n0 + 16];
    *(f16x2*)((char*)Abuf + awr[r]) = hp;
  }

  // ---- x(0) gather straight from global T2g
  const char* T2b = (const char*)T2g;
  f16x2 xv[4];
  #pragma unroll
  for (int r = 0; r < 4; ++r) {
    int v0 = inp[(size_t)(bb0 + (g << 2) + r) * Sn];
    xv[r] = *(const f16x2*)(T2b + v0 * 512 + xoff);
  }
  __syncthreads();

  char* hexpb = (char*)out_base;
  float* hfin = out_base + (size_t)Bn * Sn * Vn;

  char* hexp[4];
  #pragma unroll
  for (int r = 0; r < 4; ++r)
    hexp[r] = hexpb + ((size_t)(bb0 + (g << 2) + r) * Sn) * 512 + xoff;

  #pragma unroll 1
  for (int t = 0; t < Sn; ++t) {
    const int roff = (t & 1) << 13;
    const int woff = roff ^ 8192;

    // A-frag reads (own k-half)
    const char* ab = (const char*)Abuf + roff;
    f16x8 af0 = *(const f16x8*)(ab + ard[0]);
    f16x8 af1 = *(const f16x8*)(ab + ard[1]);
    f16x8 af2 = *(const f16x8*)(ab + ard[2]);
    f16x8 af3 = *(const f16x8*)(ab + ard[3]);

    // prefetch x(t+1): idx dword (DS) -> 4 global 4B gathers (VMEM, L2-hot)
    int tn = (t + 1 < Sn) ? t + 1 : t;
    unsigned int iv = *(const unsigned int*)(idxb + tn * 16 + (g << 2));
    f16x2 xn[4];
    #pragma unroll
    for (int r = 0; r < 4; ++r) {
      int v = (iv >> (r << 3)) & 255;
      xn[r] = *(const f16x2*)(T2b + v * 512 + xoff);
    }

    // acc init: x folds into the finalized chunks
    f32x4 acc[4];
    #pragma unroll
    for (int r = 0; r < 4; ++r) {
      acc[cbf0][r]     = (float)xv[r][0];
      acc[cbf0 + 1][r] = (float)xv[r][1];
      acc[cbo0][r]     = 0.f;
      acc[cbo0 + 1][r] = 0.f;
    }

    // 16 MFMAs (4 chains x 4 deep)
    acc[0] = __builtin_amdgcn_mfma_f32_16x16x32_f16(af0, Bf[0][0], acc[0], 0, 0, 0);
    acc[1] = __builtin_amdgcn_mfma_f32_16x16x32_f16(af0, Bf[1][0], acc[1], 0, 0, 0);
    acc[2] = __builtin_amdgcn_mfma_f32_16x16x32_f16(af0, Bf[2][0], acc[2], 0, 0, 0);
    acc[3] = __builtin_amdgcn_mfma_f32_16x16x32_f16(af0, Bf[3][0], acc[3], 0, 0, 0);
    acc[0] = __builtin_amdgcn_mfma_f32_16x16x32_f16(af1, Bf[0][1], acc[0], 0, 0, 0);
    acc[1] = __builtin_amdgcn_mfma_f32_16x16x32_f16(af1, Bf[1][1], acc[1], 0, 0, 0);
    acc[2] = __builtin_amdgcn_mfma_f32_16x16x32_f16(af1, Bf[2][1], acc[2], 0, 0, 0);
    acc[3] = __builtin_amdgcn_mfma_f32_16x16x32_f16(af1, Bf[3][1], acc[3], 0, 0, 0);
    acc[0] = __builtin_amdgcn_mfma_f32_16x16x32_f16(af2, Bf[0][2], acc[0], 0, 0, 0);
    acc[1] = __builtin_amdgcn_mfma_f32_16x16x32_f16(af2, Bf[1][2], acc[1], 0, 0, 0);
    acc[2] = __builtin_amdgcn_mfma_f32_16x16x32_f16(af2, Bf[2][2], acc[2], 0, 0, 0);
    acc[3] = __builtin_amdgcn_mfma_f32_16x16x32_f16(af2, Bf[3][2], acc[3], 0, 0, 0);
    acc[0] = __builtin_amdgcn_mfma_f32_16x16x32_f16(af3, Bf[0][3], acc[0], 0, 0, 0);
    acc[1] = __builtin_amdgcn_mfma_f32_16x16x32_f16(af3, Bf[1][3], acc[1], 0, 0, 0);
    acc[2] = __builtin_amdgcn_mfma_f32_16x16x32_f16(af3, Bf[2][3], acc[2], 0, 0, 0);
    acc[3] = __builtin_amdgcn_mfma_f32_16x16x32_f16(af3, Bf[3][3], acc[3], 0, 0, 0);

    // pack + write exchanged partials (f16x8 = one b128)
    {
      union { _Float16 h[8]; f16x8 v8; } pk;
      #pragma unroll
      for (int r = 0; r < 4; ++r) {
        pk.h[r]     = (_Float16)acc[cbo0][r];
        pk.h[4 + r] = (_Float16)acc[cbo0 + 1][r];
      }
      *(f16x8*)((char*)Ppart + pown) = pk.v8;
    }
    BAR();   // partials visible

    // read partner partials, finalize: z = own + partner + x, tanh, write h
    f16x8 pp = *(const f16x8*)((const char*)Ppart + ppar);
    char* wb = (char*)Abuf + woff;
    #pragma unroll
    for (int r = 0; r < 4; ++r) {
      float z0 = acc[cbf0][r]     + (float)pp[r];
      float z1 = acc[cbf0 + 1][r] + (float)pp[4 + r];
      f16x2 hp;
      hp[0] = (_Float16)tanh_fast(z0);
      hp[1] = (_Float16)tanh_fast(z1);
      *(f16x2*)(wb + awr[r]) = hp;               // LDS dbuf
      *(f16x2*)(hexp[r] + (size_t)t * 512) = hp; // global export, no wait
    }
    #pragma unroll
    for (int r = 0; r < 4; ++r) xv[r] = xn[r];

    BAR();   // h visible for next step; WAR for partial slots
  }

  // h_final from final LDS buffer (buffer 0 after t=1023)
  #pragma unroll
  for (int r = 0; r < 4; ++r) {
    int m = (g << 2) + r;
    f16x2 hp = *(const f16x2*)((const char*)Abuf + awr[r]);
    int n0 = (cq << 6) + (cbf0 << 4) + c;
    hfin[(bb0 + m) * Hn + n0]      = (float)hp[0];
    hfin[(bb0 + m) * Hn + n0 + 16] = (float)hp[1];
  }
}

// ---------- output GEMM: 4096 blocks x 512 thr (8 waves), in place over d_out.
template <int SLOW>
__global__ __launch_bounds__(512) void k_out(const float* __restrict__ W_ho,
    const float* __restrict__ b_ho, const _Float16* __restrict__ Wp,
    float* out_base) {
  __shared__ _Float16 At[64 * 256];                 // 32 KB, row-swizzled
  __shared__ _Float16 Wl[SLOW ? Vn * Hn : 8];       // 64 KB slow path only
  const int tid = threadIdx.x;
  const int l = tid & 63;
  const int w = tid >> 6;   // 0..7
  const int g = l >> 4;
  const int c = l & 15;
  const size_t m0 = (size_t)blockIdx.x << 6;
  const _Float16* hall = (const _Float16*)out_base;

  {
    const uint4* src = (const uint4*)(hall + (m0 << 8));
    #pragma unroll
    for (int i = 0; i < 4; ++i) {
      int gg = tid + (i << 9);
      int row = gg >> 5;
      int cb16 = (gg & 31) << 4;
      uint4 d = src[gg];
      *(uint4*)((char*)At + ((row * 512 + cb16) ^ ((row & 7) << 4))) = d;
    }
  }

  const int v = (w << 4) + c;
  f16x8 Bf[8];
  if (!SLOW) {
    const _Float16* wrow = Wp + v * Hn;
    #pragma unroll
    for (int ks = 0; ks < 8; ++ks)
      Bf[ks] = *(const f16x8*)(wrow + (ks << 5) + (g << 3));
    __syncthreads();
  } else {
    {
      int sv = tid >> 2;
      int kc = (tid & 3) << 6;
      const float* srcw = W_ho + sv * Hn + kc;
      for (int e = 0; e < 64; ++e) {
        int k = kc + e;
        *(_Float16*)((char*)Wl + ((sv * 512 + (perm(k) << 1)) ^ ((sv & 7) << 4)))
            = (_Float16)srcw[e];
      }
    }
    __syncthreads();
    #pragma unroll
    for (int ks = 0; ks < 8; ++ks)
      Bf[ks] = *(const f16x8*)((const char*)Wl +
                 ((v * 512 + (ks << 6) + (g << 4)) ^ ((v & 7) << 4)));
  }
  const float bias = b_ho[v];

  #pragma unroll
  for (int mt = 0; mt < 4; ++mt) {
    f32x4 acc = {bias, bias, bias, bias};
    const int row = (mt << 4) + c;
    #pragma unroll
    for (int ks = 0; ks < 8; ++ks) {
      f16x8 a = *(const f16x8*)((const char*)At +
                  ((row * 512 + (ks << 6) + (g << 4)) ^ ((row & 7) << 4)));
      acc = __builtin_amdgcn_mfma_f32_16x16x32_f16(a, Bf[ks], acc, 0, 0, 0);
    }
    float* orow = out_base + (m0 + (mt << 4) + (g << 2)) * Vn + v;
    orow[0]      = acc[0];
    orow[Vn]     = acc[1];
    orow[2 * Vn] = acc[2];
    orow[3 * Vn] = acc[3];
  }
}

extern "C" void kernel_launch(void* const* d_in, const int* in_sizes, int n_in,
                              void* d_out, int out_size, void* d_ws, size_t ws_size,
                              hipStream_t stream) {
  (void)in_sizes; (void)n_in; (void)out_size;
  const int*   inp    = (const int*)  d_in[0];
  const float* hidden = (const float*)d_in[1];
  const float* emb    = (const float*)d_in[2];
  const float* W_ih   = (const float*)d_in[3];
  const float* b_ih   = (const float*)d_in[4];
  const float* W_hh   = (const float*)d_in[5];
  const float* b_hh   = (const float*)d_in[6];
  const float* W_ho   = (const float*)d_in[7];
  const float* b_ho   = (const float*)d_in[8];
  float* out = (float*)d_out;

  const bool useWs = (ws_size >= 131072);
  _Float16* T2g = useWs ? (_Float16*)d_ws
                        : (_Float16*)(out + (size_t)Bn * Sn * Vn);
  _Float16* Wp  = useWs ? (_Float16*)((char*)d_ws + 65536) : nullptr;

  k_prep<<<dim3(useWs ? 2 * Vn : Vn), dim3(Hn), 0, stream>>>(emb, W_ih, b_ih, b_hh,
                                                             W_ho, T2g, Wp);
  k_rnn<<<dim3(Bn / 16), dim3(512), 0, stream>>>(inp, hidden, W_hh, T2g, out);
  if (useWs)
    k_out<0><<<dim3((Bn * Sn) / 64), dim3(512), 0, stream>>>(W_ho, b_ho, Wp, out);
  else
    k_out<1><<<dim3((Bn * Sn) / 64), dim3(512), 0, stream>>>(W_ho, b_ho, nullptr, out);
}

// Round 7
// 929.563 us; speedup vs baseline: 12.5712x; 12.5712x over previous
//
#include <hip/hip_runtime.h>
#include <hip/hip_bf16.h>
#include <hip/hip_fp16.h>

#define Bn 256
#define Sn 1024
#define Hn 256
#define Vn 128
#define En 128

typedef _Float16 f16x8 __attribute__((ext_vector_type(8)));
typedef _Float16 f16x4 __attribute__((ext_vector_type(4)));
typedef _Float16 f16x2 __attribute__((ext_vector_type(2)));
typedef float f32x4 __attribute__((ext_vector_type(4)));
typedef unsigned long long u64;

// column permutation: n = 64q + 16cb + c  ->  k' = 64q + 4c + cb
__device__ __forceinline__ int perm(int n) {
  return (n & 0xC0) | ((n & 15) << 2) | ((n >> 4) & 3);
}
__device__ __forceinline__ int iperm(int k) {
  return (k & 0xC0) | ((k & 3) << 4) | ((k >> 2) & 15);
}
// A-tile swizzle (row = byte>>9): XOR (row&7) into 16B-granule index
__device__ __forceinline__ int aswz(int b) { return b ^ (((b >> 9) & 7) << 4); }

__device__ __forceinline__ float tanh_fast(float z) {
  float e2 = __builtin_amdgcn_exp2f(z * 2.885390081777927f);
  return fmaf(-2.f, __builtin_amdgcn_rcpf(e2 + 1.f), 1.f);
}

#define BAR() asm volatile("s_waitcnt lgkmcnt(0)\n\ts_barrier" ::: "memory")

// ---------- prep: T2g[v][perm(h)] = f16(emb[v]·W_ih[h] + b_ih[h] + b_hh[h]);
//                  Wp[v][k'] = f16(W_ho[v][iperm(k')])
__global__ void k_prep(const float* __restrict__ emb, const float* __restrict__ W_ih,
                       const float* __restrict__ b_ih, const float* __restrict__ b_hh,
                       const float* __restrict__ W_ho,
                       _Float16* __restrict__ T2g, _Float16* __restrict__ Wp) {
  int bid = blockIdx.x, tid = threadIdx.x;
  if (bid < Vn) {
    int vv = bid, h = tid;
    const float4* e4 = (const float4*)(emb + vv * En);
    const float4* w4 = (const float4*)(W_ih + h * En);
    float acc = 0.f;
    #pragma unroll
    for (int i = 0; i < En / 4; ++i) {
      float4 a = e4[i], b = w4[i];
      acc += a.x * b.x + a.y * b.y + a.z * b.z + a.w * b.w;
    }
    T2g[vv * Hn + perm(h)] = (_Float16)(acc + b_ih[h] + b_hh[h]);
  } else if (Wp) {
    int vv = bid - Vn, kp = tid;
    Wp[vv * Hn + kp] = (_Float16)W_ho[vv * Hn + iperm(kp)];
  }
}

// ---------- recurrence: 16 blocks x 512 thr (8 waves, 2/SIMD).
// Wave (cq = w>>1, kh = w&1): col-quarter cq, k-half kh. Split-K: each wave does
// 4 A-frag reads + 16 MFMAs; exchanges the partner's col-chunk partials (f16-packed,
// one b128 LDS slot) with its SIMD-partner wave (w^1); finalizes tanh for 8 cols.
// ALL register arrays statically indexed (runtime chunk mapping lives in ADDRESSES).
__global__ __launch_bounds__(512, 1) void k_rnn(const int* __restrict__ inp,
    const float* __restrict__ hidden, const float* __restrict__ W_hh,
    const _Float16* __restrict__ T2g, float* out_base) {
  __shared__ _Float16 Abuf[2 * 16 * Hn];     // 16 KB  [m][k'] swizzled, dbuf
  __shared__ _Float16 Ppart[8 * 512];        // 8 KB   [wave][lane-slot 16B]
  __shared__ unsigned char idxb[Sn * 16];    // 16 KB  [t][m]

  const int tid = threadIdx.x;
  const int l = tid & 63;
  const int w = tid >> 6;      // 0..7
  const int cq = w >> 1;       // col quarter
  const int kh = w & 1;        // k half
  const int g = l >> 4;        // 0..3
  const int c = l & 15;
  const int bb0 = blockIdx.x << 4;

  const int cbf0 = kh << 1;            // finalized col-chunks (this wave)
  const int cbo0 = (kh ^ 1) << 1;      // exchanged col-chunks (partner finalizes)

  // ---- stage idx bytes (V=128 fits u8)
  #pragma unroll
  for (int i = 0; i < 8; ++i) {
    int gi = tid + (i << 9);           // 0..4095
    int m = gi >> 8;                   // row 0..15
    int j = gi & 255;                  // int4 index
    int4 d = ((const int4*)(inp + (size_t)(bb0 + m) * Sn))[j];
    int t0 = j << 2;
    idxb[(t0 + 0) * 16 + m] = (unsigned char)d.x;
    idxb[(t0 + 1) * 16 + m] = (unsigned char)d.y;
    idxb[(t0 + 2) * 16 + m] = (unsigned char)d.z;
    idxb[(t0 + 3) * 16 + m] = (unsigned char)d.w;
  }

  // ---- W_hh B-frags, chunk-mapped: Bf[0..1] = finalized chunks, Bf[2..3] = exchanged.
  // Register indices STATIC; wave-dependence only in the load address.
  f16x8 Bf[4][4];
  {
    const int chunkMap[4] = { cbf0, cbf0 + 1, cbo0, cbo0 + 1 };
    #pragma unroll
    for (int j4 = 0; j4 < 4; ++j4) {
      const float* wrow = W_hh + ((cq << 6) + (chunkMap[j4] << 4) + c) * Hn;
      #pragma unroll
      for (int ki = 0; ki < 4; ++ki) {
        int ks = (kh << 2) + ki;
        union { _Float16 h[8]; f16x8 v8; } u;
        #pragma unroll
        for (int j = 0; j < 8; ++j)
          u.h[j] = (_Float16)wrow[iperm((ks << 5) + (g << 3) + j)];
        Bf[j4][ki] = u.v8;
      }
    }
  }

  // per-thread LDS byte offsets (loop-invariant)
  const int xoff = (cq << 7) + (c << 3) + (kh << 2);  // byte off within 512B row
  int awr[4];
  #pragma unroll
  for (int r = 0; r < 4; ++r) awr[r] = aswz((((g << 2) + r) << 9) + xoff);
  int ard[4];
  #pragma unroll
  for (int ki = 0; ki < 4; ++ki)
    ard[ki] = aswz((c << 9) + (((kh << 2) + ki) << 6) + (g << 4));
  const int pslot = ((c << 6) + (g << 4)) ^ ((c & 7) << 4);
  const int pown = (w << 10) + pslot;
  const int ppar = ((w ^ 1) << 10) + pslot;

  // ---- initial h -> Abuf buffer 0 (each wave fills its own f16x2 slots)
  #pragma unroll
  for (int r = 0; r < 4; ++r) {
    int m = (g << 2) + r;
    int n0 = (cq << 6) + (cbf0 << 4) + c;
    f16x2 hp;
    hp[0] = (_Float16)hidden[(bb0 + m) * Hn + n0];
    hp[1] = (_Float16)hidden[(bb0 + m) * Hn + n0 + 16];
    *(f16x2*)((char*)Abuf + awr[r]) = hp;
  }

  // ---- x(0) gather straight from global T2g
  const char* T2b = (const char*)T2g;
  f16x2 xv[4];
  #pragma unroll
  for (int r = 0; r < 4; ++r) {
    int v0 = inp[(size_t)(bb0 + (g << 2) + r) * Sn];
    xv[r] = *(const f16x2*)(T2b + v0 * 512 + xoff);
  }
  __syncthreads();

  char* hexpb = (char*)out_base;
  float* hfin = out_base + (size_t)Bn * Sn * Vn;

  char* hexp[4];
  #pragma unroll
  for (int r = 0; r < 4; ++r)
    hexp[r] = hexpb + ((size_t)(bb0 + (g << 2) + r) * Sn) * 512 + xoff;

  #pragma unroll 1
  for (int t = 0; t < Sn; ++t) {
    const int roff = (t & 1) << 13;
    const int woff = roff ^ 8192;

    // A-frag reads (own k-half)
    const char* ab = (const char*)Abuf + roff;
    f16x8 af0 = *(const f16x8*)(ab + ard[0]);
    f16x8 af1 = *(const f16x8*)(ab + ard[1]);
    f16x8 af2 = *(const f16x8*)(ab + ard[2]);
    f16x8 af3 = *(const f16x8*)(ab + ard[3]);

    // prefetch x(t+1): idx dword (DS) -> 4 global 4B gathers (VMEM, L2-hot)
    int tn = (t + 1 < Sn) ? t + 1 : t;
    unsigned int iv = *(const unsigned int*)(idxb + tn * 16 + (g << 2));
    f16x2 xn[4];
    #pragma unroll
    for (int r = 0; r < 4; ++r) {
      int v = (iv >> (r << 3)) & 255;
      xn[r] = *(const f16x2*)(T2b + v * 512 + xoff);
    }

    // accumulators: STATIC names. F = finalized chunks (x folded in), E = exchanged.
    f32x4 accF0 = { (float)xv[0][0], (float)xv[1][0], (float)xv[2][0], (float)xv[3][0] };
    f32x4 accF1 = { (float)xv[0][1], (float)xv[1][1], (float)xv[2][1], (float)xv[3][1] };
    f32x4 accE0 = { 0.f, 0.f, 0.f, 0.f };
    f32x4 accE1 = { 0.f, 0.f, 0.f, 0.f };

    accF0 = __builtin_amdgcn_mfma_f32_16x16x32_f16(af0, Bf[0][0], accF0, 0, 0, 0);
    accF1 = __builtin_amdgcn_mfma_f32_16x16x32_f16(af0, Bf[1][0], accF1, 0, 0, 0);
    accE0 = __builtin_amdgcn_mfma_f32_16x16x32_f16(af0, Bf[2][0], accE0, 0, 0, 0);
    accE1 = __builtin_amdgcn_mfma_f32_16x16x32_f16(af0, Bf[3][0], accE1, 0, 0, 0);
    accF0 = __builtin_amdgcn_mfma_f32_16x16x32_f16(af1, Bf[0][1], accF0, 0, 0, 0);
    accF1 = __builtin_amdgcn_mfma_f32_16x16x32_f16(af1, Bf[1][1], accF1, 0, 0, 0);
    accE0 = __builtin_amdgcn_mfma_f32_16x16x32_f16(af1, Bf[2][1], accE0, 0, 0, 0);
    accE1 = __builtin_amdgcn_mfma_f32_16x16x32_f16(af1, Bf[3][1], accE1, 0, 0, 0);
    accF0 = __builtin_amdgcn_mfma_f32_16x16x32_f16(af2, Bf[0][2], accF0, 0, 0, 0);
    accF1 = __builtin_amdgcn_mfma_f32_16x16x32_f16(af2, Bf[1][2], accF1, 0, 0, 0);
    accE0 = __builtin_amdgcn_mfma_f32_16x16x32_f16(af2, Bf[2][2], accE0, 0, 0, 0);
    accE1 = __builtin_amdgcn_mfma_f32_16x16x32_f16(af2, Bf[3][2], accE1, 0, 0, 0);
    accF0 = __builtin_amdgcn_mfma_f32_16x16x32_f16(af3, Bf[0][3], accF0, 0, 0, 0);
    accF1 = __builtin_amdgcn_mfma_f32_16x16x32_f16(af3, Bf[1][3], accF1, 0, 0, 0);
    accE0 = __builtin_amdgcn_mfma_f32_16x16x32_f16(af3, Bf[2][3], accE0, 0, 0, 0);
    accE1 = __builtin_amdgcn_mfma_f32_16x16x32_f16(af3, Bf[3][3], accE1, 0, 0, 0);

    // pack + write exchanged partials (one b128)
    {
      union { _Float16 h[8]; f16x8 v8; } pk;
      #pragma unroll
      for (int r = 0; r < 4; ++r) {
        pk.h[r]     = (_Float16)accE0[r];
        pk.h[4 + r] = (_Float16)accE1[r];
      }
      *(f16x8*)((char*)Ppart + pown) = pk.v8;
    }
    BAR();   // partials visible

    // read partner partials, finalize: z = own + partner (+x already), tanh, write h
    f16x8 pp = *(const f16x8*)((const char*)Ppart + ppar);
    char* wb = (char*)Abuf + woff;
    #pragma unroll
    for (int r = 0; r < 4; ++r) {
      float z0 = accF0[r] + (float)pp[r];
      float z1 = accF1[r] + (float)pp[4 + r];
      f16x2 hp;
      hp[0] = (_Float16)tanh_fast(z0);
      hp[1] = (_Float16)tanh_fast(z1);
      *(f16x2*)(wb + awr[r]) = hp;               // LDS dbuf
      *(f16x2*)(hexp[r] + (size_t)t * 512) = hp; // global export, no wait
    }
    #pragma unroll
    for (int r = 0; r < 4; ++r) xv[r] = xn[r];

    BAR();   // h visible for next step; WAR for partial slots
  }

  // h_final from final LDS buffer (buffer 0 after t=1023)
  #pragma unroll
  for (int r = 0; r < 4; ++r) {
    int m = (g << 2) + r;
    f16x2 hp = *(const f16x2*)((const char*)Abuf + awr[r]);
    int n0 = (cq << 6) + (cbf0 << 4) + c;
    hfin[(bb0 + m) * Hn + n0]      = (float)hp[0];
    hfin[(bb0 + m) * Hn + n0 + 16] = (float)hp[1];
  }
}

// ---------- output GEMM: 4096 blocks x 512 thr (8 waves), in place over d_out.
template <int SLOW>
__global__ __launch_bounds__(512) void k_out(const float* __restrict__ W_ho,
    const float* __restrict__ b_ho, const _Float16* __restrict__ Wp,
    float* out_base) {
  __shared__ _Float16 At[64 * 256];                 // 32 KB, row-swizzled
  __shared__ _Float16 Wl[SLOW ? Vn * Hn : 8];       // 64 KB slow path only
  const int tid = threadIdx.x;
  const int l = tid & 63;
  const int w = tid >> 6;   // 0..7
  const int g = l >> 4;
  const int c = l & 15;
  const size_t m0 = (size_t)blockIdx.x << 6;
  const _Float16* hall = (const _Float16*)out_base;

  {
    const uint4* src = (const uint4*)(hall + (m0 << 8));
    #pragma unroll
    for (int i = 0; i < 4; ++i) {
      int gg = tid + (i << 9);
      int row = gg >> 5;
      int cb16 = (gg & 31) << 4;
      uint4 d = src[gg];
      *(uint4*)((char*)At + ((row * 512 + cb16) ^ ((row & 7) << 4))) = d;
    }
  }

  const int v = (w << 4) + c;
  f16x8 Bf[8];
  if (!SLOW) {
    const _Float16* wrow = Wp + v * Hn;
    #pragma unroll
    for (int ks = 0; ks < 8; ++ks)
      Bf[ks] = *(const f16x8*)(wrow + (ks << 5) + (g << 3));
    __syncthreads();
  } else {
    {
      int sv = tid >> 2;
      int kc = (tid & 3) << 6;
      const float* srcw = W_ho + sv * Hn + kc;
      for (int e = 0; e < 64; ++e) {
        int k = kc + e;
        *(_Float16*)((char*)Wl + ((sv * 512 + (perm(k) << 1)) ^ ((sv & 7) << 4)))
            = (_Float16)srcw[e];
      }
    }
    __syncthreads();
    #pragma unroll
    for (int ks = 0; ks < 8; ++ks)
      Bf[ks] = *(const f16x8*)((const char*)Wl +
                 ((v * 512 + (ks << 6) + (g << 4)) ^ ((v & 7) << 4)));
  }
  const float bias = b_ho[v];

  #pragma unroll
  for (int mt = 0; mt < 4; ++mt) {
    f32x4 acc = {bias, bias, bias, bias};
    const int row = (mt << 4) + c;
    #pragma unroll
    for (int ks = 0; ks < 8; ++ks) {
      f16x8 a = *(const f16x8*)((const char*)At +
                  ((row * 512 + (ks << 6) + (g << 4)) ^ ((row & 7) << 4)));
      acc = __builtin_amdgcn_mfma_f32_16x16x32_f16(a, Bf[ks], acc, 0, 0, 0);
    }
    float* orow = out_base + (m0 + (mt << 4) + (g << 2)) * Vn + v;
    orow[0]      = acc[0];
    orow[Vn]     = acc[1];
    orow[2 * Vn] = acc[2];
    orow[3 * Vn] = acc[3];
  }
}

extern "C" void kernel_launch(void* const* d_in, const int* in_sizes, int n_in,
                              void* d_out, int out_size, void* d_ws, size_t ws_size,
                              hipStream_t stream) {
  (void)in_sizes; (void)n_in; (void)out_size;
  const int*   inp    = (const int*)  d_in[0];
  const float* hidden = (const float*)d_in[1];
  const float* emb    = (const float*)d_in[2];
  const float* W_ih   = (const float*)d_in[3];
  const float* b_ih   = (const float*)d_in[4];
  const float* W_hh   = (const float*)d_in[5];
  const float* b_hh   = (const float*)d_in[6];
  const float* W_ho   = (const float*)d_in[7];
  const float* b_ho   = (const float*)d_in[8];
  float* out = (float*)d_out;

  const bool useWs = (ws_size >= 131072);
  _Float16* T2g = useWs ? (_Float16*)d_ws
                        : (_Float16*)(out + (size_t)Bn * Sn * Vn);
  _Float16* Wp  = useWs ? (_Float16*)((char*)d_ws + 65536) : nullptr;

  k_prep<<<dim3(useWs ? 2 * Vn : Vn), dim3(Hn), 0, stream>>>(emb, W_ih, b_ih, b_hh,
                                                             W_ho, T2g, Wp);
  k_rnn<<<dim3(Bn / 16), dim3(512), 0, stream>>>(inp, hidden, W_hh, T2g, out);
  if (useWs)
    k_out<0><<<dim3((Bn * Sn) / 64), dim3(512), 0, stream>>>(W_ho, b_ho, Wp, out);
  else
    k_out<1><<<dim3((Bn * Sn) / 64), dim3(512), 0, stream>>>(W_ho, b_ho, nullptr, out);
}

// Round 9
// 898.031 us; speedup vs baseline: 13.0126x; 1.0351x over previous
//
#include <hip/hip_runtime.h>
#include <hip/hip_bf16.h>
#include <hip/hip_fp16.h>

#define Bn 256
#define Sn 1024
#define Hn 256
#define Vn 128
#define En 128

typedef _Float16 f16x8 __attribute__((ext_vector_type(8)));
typedef _Float16 f16x4 __attribute__((ext_vector_type(4)));
typedef _Float16 f16x2 __attribute__((ext_vector_type(2)));
typedef __fp16 fp16x2 __attribute__((ext_vector_type(2)));   // cvt_pkrtz native type
typedef float f32x4 __attribute__((ext_vector_type(4)));
typedef unsigned long long u64;
typedef unsigned int u32;

#define LOG2E2 2.885390081777927f   // 2*log2(e), folded into W_hh and T2

// column permutation: n = 64q + 16cb + c  ->  k' = 64q + 4c + cb
__device__ __forceinline__ int perm(int n) {
  return (n & 0xC0) | ((n & 15) << 2) | ((n >> 4) & 3);
}
__device__ __forceinline__ int iperm(int k) {
  return (k & 0xC0) | ((k & 3) << 4) | ((k >> 2) & 15);
}
// A-tile swizzle (row = byte>>9): XOR (row&7) into 16B-granule index
__device__ __forceinline__ int aswz(int b) { return b ^ (((b >> 9) & 7) << 4); }

#define BAR() asm volatile("s_waitcnt lgkmcnt(0)\n\ts_barrier" ::: "memory")

// ---------- prep: T2g[v][perm(h)] = f16( (emb[v]·W_ih[h] + b_ih[h] + b_hh[h]) * 2log2e )
//                  Wp[v][k'] = f16(W_ho[v][iperm(k')])   (UNscaled, for k_out)
__global__ void k_prep(const float* __restrict__ emb, const float* __restrict__ W_ih,
                       const float* __restrict__ b_ih, const float* __restrict__ b_hh,
                       const float* __restrict__ W_ho,
                       _Float16* __restrict__ T2g, _Float16* __restrict__ Wp) {
  int bid = blockIdx.x, tid = threadIdx.x;
  if (bid < Vn) {
    int vv = bid, h = tid;
    const float4* e4 = (const float4*)(emb + vv * En);
    const float4* w4 = (const float4*)(W_ih + h * En);
    float acc = 0.f;
    #pragma unroll
    for (int i = 0; i < En / 4; ++i) {
      float4 a = e4[i], b = w4[i];
      acc += a.x * b.x + a.y * b.y + a.z * b.z + a.w * b.w;
    }
    T2g[vv * Hn + perm(h)] = (_Float16)((acc + b_ih[h] + b_hh[h]) * LOG2E2);
  } else if (Wp) {
    int vv = bid - Vn, kp = tid;
    Wp[vv * Hn + kp] = (_Float16)W_ho[vv * Hn + iperm(kp)];
  }
}

#define MF(ks) \
  acc0 = __builtin_amdgcn_mfma_f32_16x16x32_f16(af##ks, Bf[0][ks], acc0, 0, 0, 0); \
  acc1 = __builtin_amdgcn_mfma_f32_16x16x32_f16(af##ks, Bf[1][ks], acc1, 0, 0, 0); \
  acc2 = __builtin_amdgcn_mfma_f32_16x16x32_f16(af##ks, Bf[2][ks], acc2, 0, 0, 0); \
  acc3 = __builtin_amdgcn_mfma_f32_16x16x32_f16(af##ks, Bf[3][ks], acc3, 0, 0, 0);

// ---------- recurrence: 16 blocks x 256 thr (4 waves). Wave w: cols [64w,64w+64).
// One lgkm-only barrier/step. W_hh pre-scaled by 2log2e so MFMA output feeds exp2
// directly. Finalize: f32 exp2/rcp + cvt_pkrtz pack. Uniform base + u32 voffsets.
__global__ __launch_bounds__(256, 1) void k_rnn(const int* __restrict__ inp,
    const float* __restrict__ hidden, const float* __restrict__ W_hh,
    const _Float16* __restrict__ T2g, float* out_base) {
  __shared__ _Float16 Abuf[2 * 16 * Hn];     // 16 KB  [m][k'] swizzled, dbuf
  __shared__ unsigned char idxb[Sn * 16];    // 16 KB  [t][m]

  const int tid = threadIdx.x;
  const int l = tid & 63;
  const int w = tid >> 6;   // 0..3
  const int g = l >> 4;     // 0..3
  const int c = l & 15;
  const int bb0 = blockIdx.x << 4;

  // ---- stage idx bytes (V=128 fits u8)
  for (int m = 0; m < 16; ++m) {
    int4 d = ((const int4*)(inp + (size_t)(bb0 + m) * Sn))[tid];
    int t0 = tid << 2;
    idxb[(t0 + 0) * 16 + m] = (unsigned char)d.x;
    idxb[(t0 + 1) * 16 + m] = (unsigned char)d.y;
    idxb[(t0 + 2) * 16 + m] = (unsigned char)d.z;
    idxb[(t0 + 3) * 16 + m] = (unsigned char)d.w;
  }

  // ---- W_hh B-frags (pre-scaled): Bf[cb][ks] elem j = 2log2e * W_hh[64w+16cb+c][iperm(32ks+8g+j)]
  f16x8 Bf[4][8];
  #pragma unroll
  for (int cb = 0; cb < 4; ++cb) {
    const float* wrow = W_hh + ((w << 6) + (cb << 4) + c) * Hn;
    #pragma unroll
    for (int ks = 0; ks < 8; ++ks) {
      union { _Float16 h[8]; f16x8 v8; } u;
      #pragma unroll
      for (int j = 0; j < 8; ++j)
        u.h[j] = (_Float16)(wrow[iperm((ks << 5) + (g << 3) + j)] * LOG2E2);
      Bf[cb][ks] = u.v8;
    }
  }

  // per-thread LDS byte offsets (loop-invariant)
  const int xoff = (w << 7) + (c << 3);
  int awr[4];
  #pragma unroll
  for (int r = 0; r < 4; ++r) awr[r] = aswz((((g << 2) + r) << 9) + xoff);
  int ard[8];
  #pragma unroll
  for (int ks = 0; ks < 8; ++ks) ard[ks] = aswz((c << 9) + (ks << 6) + (g << 4));

  // ---- initial h -> Abuf buffer 0
  #pragma unroll
  for (int r = 0; r < 4; ++r) {
    int m = (g << 2) + r;
    f16x4 hp;
    #pragma unroll
    for (int cb = 0; cb < 4; ++cb)
      hp[cb] = (_Float16)hidden[(bb0 + m) * Hn + (w << 6) + (cb << 4) + c];
    *(u64*)((char*)Abuf + awr[r]) = *(u64*)&hp;
  }

  // ---- x(0) gather from T2g (uniform base + u32 offset)
  const char* T2b = (const char*)T2g;
  f16x4 xv[4];
  #pragma unroll
  for (int r = 0; r < 4; ++r) {
    u32 v0 = (u32)inp[(size_t)(bb0 + (g << 2) + r) * Sn];
    xv[r] = *(const f16x4*)(T2b + (v0 << 9) + xoff);
  }
  __syncthreads();

  char* outb = (char*)out_base;
  float* hfin = out_base + (size_t)Bn * Sn * Vn;

  // export u32 voffsets (byte), advanced by 512/step
  u32 vo[4];
  #pragma unroll
  for (int r = 0; r < 4; ++r)
    vo[r] = (u32)(((bb0 + (g << 2) + r) * Sn) * 512) + (u32)xoff;

  #pragma unroll 1
  for (int t = 0; t < Sn; ++t) {
    const int roff = (t & 1) << 13;
    const int woff = roff ^ 8192;

    // A-frag reads (critical path first)
    const char* ab = (const char*)Abuf + roff;
    f16x8 af0 = *(const f16x8*)(ab + ard[0]);
    f16x8 af1 = *(const f16x8*)(ab + ard[1]);
    f16x8 af2 = *(const f16x8*)(ab + ard[2]);
    f16x8 af3 = *(const f16x8*)(ab + ard[3]);
    f16x8 af4 = *(const f16x8*)(ab + ard[4]);
    f16x8 af5 = *(const f16x8*)(ab + ard[5]);
    f16x8 af6 = *(const f16x8*)(ab + ard[6]);
    f16x8 af7 = *(const f16x8*)(ab + ard[7]);

    // prefetch x(t+1): idx dword (DS) -> 4 x 8B gathers (VMEM loads, before stores)
    int tn = (t + 1 < Sn) ? t + 1 : t;
    u32 iv = *(const u32*)(idxb + tn * 16 + (g << 2));
    f16x4 xn[4];
    xn[0] = *(const f16x4*)(T2b + ((iv & 255u) << 9) + xoff);
    xn[1] = *(const f16x4*)(T2b + (((iv >> 8) & 255u) << 9) + xoff);
    xn[2] = *(const f16x4*)(T2b + (((iv >> 16) & 255u) << 9) + xoff);
    xn[3] = *(const f16x4*)(T2b + ((iv >> 24) << 9) + xoff);

    // acc init folds (pre-scaled) x
    f32x4 acc0 = { (float)xv[0][0], (float)xv[1][0], (float)xv[2][0], (float)xv[3][0] };
    f32x4 acc1 = { (float)xv[0][1], (float)xv[1][1], (float)xv[2][1], (float)xv[3][1] };
    f32x4 acc2 = { (float)xv[0][2], (float)xv[1][2], (float)xv[2][2], (float)xv[3][2] };
    f32x4 acc3 = { (float)xv[0][3], (float)xv[1][3], (float)xv[2][3], (float)xv[3][3] };

    MF(0) MF(1) MF(2) MF(3) MF(4) MF(5) MF(6) MF(7)

    // finalize: z' already scaled -> tanh = 1 - 2/(exp2(z')+1); pack via cvt_pkrtz
    char* wb = (char*)Abuf + woff;
    #pragma unroll
    for (int r = 0; r < 4; ++r) {
      float e0 = __builtin_amdgcn_exp2f(acc0[r]);
      float e1 = __builtin_amdgcn_exp2f(acc1[r]);
      float e2 = __builtin_amdgcn_exp2f(acc2[r]);
      float e3 = __builtin_amdgcn_exp2f(acc3[r]);
      float h0 = fmaf(-2.f, __builtin_amdgcn_rcpf(e0 + 1.f), 1.f);
      float h1 = fmaf(-2.f, __builtin_amdgcn_rcpf(e1 + 1.f), 1.f);
      float h2 = fmaf(-2.f, __builtin_amdgcn_rcpf(e2 + 1.f), 1.f);
      float h3 = fmaf(-2.f, __builtin_amdgcn_rcpf(e3 + 1.f), 1.f);
      union { fp16x2 p[2]; u64 q; } hp;
      hp.p[0] = __builtin_amdgcn_cvt_pkrtz(h0, h1);
      hp.p[1] = __builtin_amdgcn_cvt_pkrtz(h2, h3);
      *(u64*)(wb + awr[r]) = hp.q;           // LDS dbuf (b64)
      *(u64*)(outb + vo[r]) = hp.q;          // global export (saddr + u32 voffset)
      vo[r] += 512;
    }
    #pragma unroll
    for (int r = 0; r < 4; ++r) xv[r] = xn[r];

    BAR();   // lgkm drain only; exports stay in flight
  }

  // h_final from final LDS buffer (buffer 0 after t=1023)
  #pragma unroll
  for (int r = 0; r < 4; ++r) {
    int m = (g << 2) + r;
    f16x4 hp = *(const f16x4*)((const char*)Abuf + awr[r]);
    #pragma unroll
    for (int cb = 0; cb < 4; ++cb)
      hfin[(bb0 + m) * Hn + (w << 6) + (cb << 4) + c] = (float)hp[cb];
  }
}

// ---------- output GEMM: 4096 blocks x 512 thr (8 waves), in place over d_out.
template <int SLOW>
__global__ __launch_bounds__(512) void k_out(const float* __restrict__ W_ho,
    const float* __restrict__ b_ho, const _Float16* __restrict__ Wp,
    float* out_base) {
  __shared__ _Float16 At[64 * 256];                 // 32 KB, row-swizzled
  __shared__ _Float16 Wl[SLOW ? Vn * Hn : 8];       // 64 KB slow path only
  const int tid = threadIdx.x;
  const int l = tid & 63;
  const int w = tid >> 6;   // 0..7
  const int g = l >> 4;
  const int c = l & 15;
  const size_t m0 = (size_t)blockIdx.x << 6;
  const _Float16* hall = (const _Float16*)out_base;

  {
    const uint4* src = (const uint4*)(hall + (m0 << 8));
    #pragma unroll
    for (int i = 0; i < 4; ++i) {
      int gg = tid + (i << 9);
      int row = gg >> 5;
      int cb16 = (gg & 31) << 4;
      uint4 d = src[gg];
      *(uint4*)((char*)At + ((row * 512 + cb16) ^ ((row & 7) << 4))) = d;
    }
  }

  const int v = (w << 4) + c;
  f16x8 Bf[8];
  if (!SLOW) {
    const _Float16* wrow = Wp + v * Hn;
    #pragma unroll
    for (int ks = 0; ks < 8; ++ks)
      Bf[ks] = *(const f16x8*)(wrow + (ks << 5) + (g << 3));
    __syncthreads();
  } else {
    {
      int sv = tid >> 2;
      int kc = (tid & 3) << 6;
      const float* srcw = W_ho + sv * Hn + kc;
      for (int e = 0; e < 64; ++e) {
        int k = kc + e;
        *(_Float16*)((char*)Wl + ((sv * 512 + (perm(k) << 1)) ^ ((sv & 7) << 4)))
            = (_Float16)srcw[e];
      }
    }
    __syncthreads();
    #pragma unroll
    for (int ks = 0; ks < 8; ++ks)
      Bf[ks] = *(const f16x8*)((const char*)Wl +
                 ((v * 512 + (ks << 6) + (g << 4)) ^ ((v & 7) << 4)));
  }
  const float bias = b_ho[v];

  #pragma unroll
  for (int mt = 0; mt < 4; ++mt) {
    f32x4 acc = {bias, bias, bias, bias};
    const int row = (mt << 4) + c;
    #pragma unroll
    for (int ks = 0; ks < 8; ++ks) {
      f16x8 a = *(const f16x8*)((const char*)At +
                  ((row * 512 + (ks << 6) + (g << 4)) ^ ((row & 7) << 4)));
      acc = __builtin_amdgcn_mfma_f32_16x16x32_f16(a, Bf[ks], acc, 0, 0, 0);
    }
    float* orow = out_base + (m0 + (mt << 4) + (g << 2)) * Vn + v;
    orow[0]      = acc[0];
    orow[Vn]     = acc[1];
    orow[2 * Vn] = acc[2];
    orow[3 * Vn] = acc[3];
  }
}

extern "C" void kernel_launch(void* const* d_in, const int* in_sizes, int n_in,
                              void* d_out, int out_size, void* d_ws, size_t ws_size,
                              hipStream_t stream) {
  (void)in_sizes; (void)n_in; (void)out_size;
  const int*   inp    = (const int*)  d_in[0];
  const float* hidden = (const float*)d_in[1];
  const float* emb    = (const float*)d_in[2];
  const float* W_ih   = (const float*)d_in[3];
  const float* b_ih   = (const float*)d_in[4];
  const float* W_hh   = (const float*)d_in[5];
  const float* b_hh   = (const float*)d_in[6];
  const float* W_ho   = (const float*)d_in[7];
  const float* b_ho   = (const float*)d_in[8];
  float* out = (float*)d_out;

  const bool useWs = (ws_size >= 131072);
  _Float16* T2g = useWs ? (_Float16*)d_ws
                        : (_Float16*)(out + (size_t)Bn * Sn * Vn);
  _Float16* Wp  = useWs ? (_Float16*)((char*)d_ws + 65536) : nullptr;

  k_prep<<<dim3(useWs ? 2 * Vn : Vn), dim3(Hn), 0, stream>>>(emb, W_ih, b_ih, b_hh,
                                                             W_ho, T2g, Wp);
  k_rnn<<<dim3(Bn / 16), dim3(256), 0, stream>>>(inp, hidden, W_hh, T2g, out);
  if (useWs)
    k_out<0><<<dim3((Bn * Sn) / 64), dim3(512), 0, stream>>>(W_ho, b_ho, Wp, out);
  else
    k_out<1><<<dim3((Bn * Sn) / 64), dim3(512), 0, stream>>>(W_ho, b_ho, nullptr, out);
}

// Round 10
// 813.581 us; speedup vs baseline: 14.3633x; 1.1038x over previous
//
#include <hip/hip_runtime.h>
#include <hip/hip_bf16.h>
#include <hip/hip_fp16.h>

#define Bn 256
#define Sn 1024
#define Hn 256
#define Vn 128
#define En 128

typedef _Float16 f16x8 __attribute__((ext_vector_type(8)));
typedef _Float16 f16x4 __attribute__((ext_vector_type(4)));
typedef _Float16 f16x2 __attribute__((ext_vector_type(2)));
typedef float f32x4 __attribute__((ext_vector_type(4)));
typedef unsigned long long u64;
typedef unsigned int u32;

#define LOG2E2 2.885390081777927f   // 2*log2(e), folded into W_hh and T2

// column permutation: n -> k' ; byte(k') pairs adjacent for (2w+cb2) pairs
__device__ __forceinline__ int perm(int n) {
  return (n & 0xC0) | ((n & 15) << 2) | ((n >> 4) & 3);
}
__device__ __forceinline__ int iperm(int k) {
  return (k & 0xC0) | ((k & 3) << 4) | ((k >> 2) & 15);
}
// A-tile swizzle (row = byte>>9): XOR (row&7) into 16B-granule index
__device__ __forceinline__ int aswz(int b) { return b ^ (((b >> 9) & 7) << 4); }

#define BAR() asm volatile("s_waitcnt lgkmcnt(0)\n\ts_barrier" ::: "memory")

// ---------- prep: T2g[v][perm(h)] = f16( (emb[v]·W_ih[h] + b_ih[h] + b_hh[h]) * 2log2e )
//                  Wp[v][k'] = f16(W_ho[v][iperm(k')])   (UNscaled, for k_out)
__global__ void k_prep(const float* __restrict__ emb, const float* __restrict__ W_ih,
                       const float* __restrict__ b_ih, const float* __restrict__ b_hh,
                       const float* __restrict__ W_ho,
                       _Float16* __restrict__ T2g, _Float16* __restrict__ Wp) {
  int bid = blockIdx.x, tid = threadIdx.x;
  if (bid < Vn) {
    int vv = bid, h = tid;
    const float4* e4 = (const float4*)(emb + vv * En);
    const float4* w4 = (const float4*)(W_ih + h * En);
    float acc = 0.f;
    #pragma unroll
    for (int i = 0; i < En / 4; ++i) {
      float4 a = e4[i], b = w4[i];
      acc += a.x * b.x + a.y * b.y + a.z * b.z + a.w * b.w;
    }
    T2g[vv * Hn + perm(h)] = (_Float16)((acc + b_ih[h] + b_hh[h]) * LOG2E2);
  } else if (Wp) {
    int vv = bid - Vn, kp = tid;
    Wp[vv * Hn + kp] = (_Float16)W_ho[vv * Hn + iperm(kp)];
  }
}

#define MF(ks) \
  acc0 = __builtin_amdgcn_mfma_f32_16x16x32_f16(af##ks, Bf[0][ks], acc0, 0, 0, 0); \
  acc1 = __builtin_amdgcn_mfma_f32_16x16x32_f16(af##ks, Bf[1][ks], acc1, 0, 0, 0);

// ---------- recurrence: 16 blocks x 512 thr (8 waves, 2 per SIMD).
// Wave w owns cols [32w, 32w+32) = 2 col-blocks, FULL K=256 (no exchange).
// 2 independent waves per SIMD -> tanh/DS of one overlaps MFMA of the other.
// One lgkm-only barrier/step; exports fire-and-forget; RTN h-rounding.
__global__ __launch_bounds__(512, 1) void k_rnn(const int* __restrict__ inp,
    const float* __restrict__ hidden, const float* __restrict__ W_hh,
    const _Float16* __restrict__ T2g, float* out_base) {
  __shared__ _Float16 Abuf[2 * 16 * Hn];     // 16 KB  [m][k'] swizzled, dbuf
  __shared__ unsigned char idxb[Sn * 16];    // 16 KB  [t][m]

  const int tid = threadIdx.x;
  const int l = tid & 63;
  const int w = tid >> 6;   // 0..7
  const int g = l >> 4;     // 0..3
  const int c = l & 15;
  const int bb0 = blockIdx.x << 4;

  // ---- stage idx bytes (V=128 fits u8); 512 thr x 8 = 16 rows x 256 int4
  #pragma unroll
  for (int i = 0; i < 8; ++i) {
    int gi = tid + (i << 9);
    int m = gi >> 8;
    int j = gi & 255;
    int4 d = ((const int4*)(inp + (size_t)(bb0 + m) * Sn))[j];
    int t0 = j << 2;
    idxb[(t0 + 0) * 16 + m] = (unsigned char)d.x;
    idxb[(t0 + 1) * 16 + m] = (unsigned char)d.y;
    idxb[(t0 + 2) * 16 + m] = (unsigned char)d.z;
    idxb[(t0 + 3) * 16 + m] = (unsigned char)d.w;
  }

  // ---- W_hh B-frags (pre-scaled): wave w, col n = 32w + 16*cb2 + c
  f16x8 Bf[2][8];
  #pragma unroll
  for (int cb2 = 0; cb2 < 2; ++cb2) {
    const float* wrow = W_hh + ((w << 5) + (cb2 << 4) + c) * Hn;
    #pragma unroll
    for (int ks = 0; ks < 8; ++ks) {
      union { _Float16 h[8]; f16x8 v8; } u;
      #pragma unroll
      for (int j = 0; j < 8; ++j)
        u.h[j] = (_Float16)(wrow[iperm((ks << 5) + (g << 3) + j)] * LOG2E2);
      Bf[cb2][ks] = u.v8;
    }
  }

  // per-thread LDS byte offsets (loop-invariant)
  // xoff: bytes of k' pair for (n0 = 32w + c, n1 = n0 + 16): adjacent 4B
  const int xoff = ((w >> 1) << 7) + (c << 3) + ((w & 1) << 2);
  int awr[4];
  #pragma unroll
  for (int r = 0; r < 4; ++r) awr[r] = aswz((((g << 2) + r) << 9) + xoff);
  int ard[8];
  #pragma unroll
  for (int ks = 0; ks < 8; ++ks) ard[ks] = aswz((c << 9) + (ks << 6) + (g << 4));

  // ---- initial h -> Abuf buffer 0 (f16x2 = b32 per lane per r)
  #pragma unroll
  for (int r = 0; r < 4; ++r) {
    int m = (g << 2) + r;
    union { _Float16 h[2]; u32 q; } hp;
    hp.h[0] = (_Float16)hidden[(bb0 + m) * Hn + (w << 5) + c];
    hp.h[1] = (_Float16)hidden[(bb0 + m) * Hn + (w << 5) + 16 + c];
    *(u32*)((char*)Abuf + awr[r]) = hp.q;
  }

  // ---- x(0) gather from T2g (uniform base + u32 offset, 4B per lane)
  const char* T2b = (const char*)T2g;
  f16x2 xv[4];
  #pragma unroll
  for (int r = 0; r < 4; ++r) {
    u32 v0 = (u32)inp[(size_t)(bb0 + (g << 2) + r) * Sn];
    xv[r] = *(const f16x2*)(T2b + (v0 << 9) + xoff);
  }
  __syncthreads();

  char* outb = (char*)out_base;
  float* hfin = out_base + (size_t)Bn * Sn * Vn;

  // export u32 voffsets (byte), advanced by 512/step
  u32 vo[4];
  #pragma unroll
  for (int r = 0; r < 4; ++r)
    vo[r] = (u32)(((bb0 + (g << 2) + r) * Sn) * 512) + (u32)xoff;

  #pragma unroll 1
  for (int t = 0; t < Sn; ++t) {
    const int roff = (t & 1) << 13;
    const int woff = roff ^ 8192;

    // A-frag reads (full K; critical path first)
    const char* ab = (const char*)Abuf + roff;
    f16x8 af0 = *(const f16x8*)(ab + ard[0]);
    f16x8 af1 = *(const f16x8*)(ab + ard[1]);
    f16x8 af2 = *(const f16x8*)(ab + ard[2]);
    f16x8 af3 = *(const f16x8*)(ab + ard[3]);
    f16x8 af4 = *(const f16x8*)(ab + ard[4]);
    f16x8 af5 = *(const f16x8*)(ab + ard[5]);
    f16x8 af6 = *(const f16x8*)(ab + ard[6]);
    f16x8 af7 = *(const f16x8*)(ab + ard[7]);

    // prefetch x(t+1): idx dword (DS) -> 4 x 4B gathers (VMEM, loads before stores)
    int tn = (t + 1 < Sn) ? t + 1 : t;
    u32 iv = *(const u32*)(idxb + tn * 16 + (g << 2));
    f16x2 xn[4];
    xn[0] = *(const f16x2*)(T2b + ((iv & 255u) << 9) + xoff);
    xn[1] = *(const f16x2*)(T2b + (((iv >> 8) & 255u) << 9) + xoff);
    xn[2] = *(const f16x2*)(T2b + (((iv >> 16) & 255u) << 9) + xoff);
    xn[3] = *(const f16x2*)(T2b + ((iv >> 24) << 9) + xoff);

    // acc init folds (pre-scaled) x
    f32x4 acc0 = { (float)xv[0][0], (float)xv[1][0], (float)xv[2][0], (float)xv[3][0] };
    f32x4 acc1 = { (float)xv[0][1], (float)xv[1][1], (float)xv[2][1], (float)xv[3][1] };

    MF(0) MF(1) MF(2) MF(3) MF(4) MF(5) MF(6) MF(7)

    // finalize: tanh = 1 - 2/(exp2(z')+1); RTN pack (unbiased -- absmax!)
    char* wb = (char*)Abuf + woff;
    #pragma unroll
    for (int r = 0; r < 4; ++r) {
      float e0 = __builtin_amdgcn_exp2f(acc0[r]);
      float e1 = __builtin_amdgcn_exp2f(acc1[r]);
      float h0 = fmaf(-2.f, __builtin_amdgcn_rcpf(e0 + 1.f), 1.f);
      float h1 = fmaf(-2.f, __builtin_amdgcn_rcpf(e1 + 1.f), 1.f);
      union { _Float16 h[2]; u32 q; } hp;
      hp.h[0] = (_Float16)h0;
      hp.h[1] = (_Float16)h1;
      *(u32*)(wb + awr[r]) = hp.q;           // LDS dbuf (b32)
      *(u32*)(outb + vo[r]) = hp.q;          // global export (no vmcnt wait)
      vo[r] += 512;
    }
    #pragma unroll
    for (int r = 0; r < 4; ++r) xv[r] = xn[r];

    BAR();   // lgkm drain only; exports stay in flight
  }

  // h_final from final LDS buffer (buffer 0 after t=1023)
  #pragma unroll
  for (int r = 0; r < 4; ++r) {
    int m = (g << 2) + r;
    union { _Float16 h[2]; u32 q; } hp;
    hp.q = *(const u32*)((const char*)Abuf + awr[r]);
    hfin[(bb0 + m) * Hn + (w << 5) + c]      = (float)hp.h[0];
    hfin[(bb0 + m) * Hn + (w << 5) + 16 + c] = (float)hp.h[1];
  }
}

// ---------- output GEMM: 4096 blocks x 512 thr (8 waves), in place over d_out.
template <int SLOW>
__global__ __launch_bounds__(512) void k_out(const float* __restrict__ W_ho,
    const float* __restrict__ b_ho, const _Float16* __restrict__ Wp,
    float* out_base) {
  __shared__ _Float16 At[64 * 256];                 // 32 KB, row-swizzled
  __shared__ _Float16 Wl[SLOW ? Vn * Hn : 8];       // 64 KB slow path only
  const int tid = threadIdx.x;
  const int l = tid & 63;
  const int w = tid >> 6;   // 0..7
  const int g = l >> 4;
  const int c = l & 15;
  const size_t m0 = (size_t)blockIdx.x << 6;
  const _Float16* hall = (const _Float16*)out_base;

  {
    const uint4* src = (const uint4*)(hall + (m0 << 8));
    #pragma unroll
    for (int i = 0; i < 4; ++i) {
      int gg = tid + (i << 9);
      int row = gg >> 5;
      int cb16 = (gg & 31) << 4;
      uint4 d = src[gg];
      *(uint4*)((char*)At + ((row * 512 + cb16) ^ ((row & 7) << 4))) = d;
    }
  }

  const int v = (w << 4) + c;
  f16x8 Bf[8];
  if (!SLOW) {
    const _Float16* wrow = Wp + v * Hn;
    #pragma unroll
    for (int ks = 0; ks < 8; ++ks)
      Bf[ks] = *(const f16x8*)(wrow + (ks << 5) + (g << 3));
    __syncthreads();
  } else {
    {
      int sv = tid >> 2;
      int kc = (tid & 3) << 6;
      const float* srcw = W_ho + sv * Hn + kc;
      for (int e = 0; e < 64; ++e) {
        int k = kc + e;
        *(_Float16*)((char*)Wl + ((sv * 512 + (perm(k) << 1)) ^ ((sv & 7) << 4)))
            = (_Float16)srcw[e];
      }
    }
    __syncthreads();
    #pragma unroll
    for (int ks = 0; ks < 8; ++ks)
      Bf[ks] = *(const f16x8*)((const char*)Wl +
                 ((v * 512 + (ks << 6) + (g << 4)) ^ ((v & 7) << 4)));
  }
  const float bias = b_ho[v];

  #pragma unroll
  for (int mt = 0; mt < 4; ++mt) {
    f32x4 acc = {bias, bias, bias, bias};
    const int row = (mt << 4) + c;
    #pragma unroll
    for (int ks = 0; ks < 8; ++ks) {
      f16x8 a = *(const f16x8*)((const char*)At +
                  ((row * 512 + (ks << 6) + (g << 4)) ^ ((row & 7) << 4)));
      acc = __builtin_amdgcn_mfma_f32_16x16x32_f16(a, Bf[ks], acc, 0, 0, 0);
    }
    float* orow = out_base + (m0 + (mt << 4) + (g << 2)) * Vn + v;
    orow[0]      = acc[0];
    orow[Vn]     = acc[1];
    orow[2 * Vn] = acc[2];
    orow[3 * Vn] = acc[3];
  }
}

extern "C" void kernel_launch(void* const* d_in, const int* in_sizes, int n_in,
                              void* d_out, int out_size, void* d_ws, size_t ws_size,
                              hipStream_t stream) {
  (void)in_sizes; (void)n_in; (void)out_size;
  const int*   inp    = (const int*)  d_in[0];
  const float* hidden = (const float*)d_in[1];
  const float* emb    = (const float*)d_in[2];
  const float* W_ih   = (const float*)d_in[3];
  const float* b_ih   = (const float*)d_in[4];
  const float* W_hh   = (const float*)d_in[5];
  const float* b_hh   = (const float*)d_in[6];
  const float* W_ho   = (const float*)d_in[7];
  const float* b_ho   = (const float*)d_in[8];
  float* out = (float*)d_out;

  const bool useWs = (ws_size >= 131072);
  _Float16* T2g = useWs ? (_Float16*)d_ws
                        : (_Float16*)(out + (size_t)Bn * Sn * Vn);
  _Float16* Wp  = useWs ? (_Float16*)((char*)d_ws + 65536) : nullptr;

  k_prep<<<dim3(useWs ? 2 * Vn : Vn), dim3(Hn), 0, stream>>>(emb, W_ih, b_ih, b_hh,
                                                             W_ho, T2g, Wp);
  k_rnn<<<dim3(Bn / 16), dim3(512), 0, stream>>>(inp, hidden, W_hh, T2g, out);
  if (useWs)
    k_out<0><<<dim3((Bn * Sn) / 64), dim3(512), 0, stream>>>(W_ho, b_ho, Wp, out);
  else
    k_out<1><<<dim3((Bn * Sn) / 64), dim3(512), 0, stream>>>(W_ho, b_ho, nullptr, out);
}

// Round 11
// 696.652 us; speedup vs baseline: 16.7741x; 1.1678x over previous
//
#include <hip/hip_runtime.h>
#include <hip/hip_bf16.h>
#include <hip/hip_fp16.h>

#define Bn 256
#define Sn 1024
#define Hn 256
#define Vn 128
#define En 128

typedef _Float16 f16x8 __attribute__((ext_vector_type(8)));
typedef _Float16 f16x4 __attribute__((ext_vector_type(4)));
typedef _Float16 f16x2 __attribute__((ext_vector_type(2)));
typedef float f32x4 __attribute__((ext_vector_type(4)));
typedef unsigned long long u64;
typedef unsigned int u32;

#define LOG2E2 2.885390081777927f   // 2*log2(e), folded into W_hh and T2

// NEW column permutation: n = 32w + 16cb2 + c  ->  k' = 32w + 2c + cb2
__device__ __forceinline__ int perm2(int n) {
  return (n & 0xE0) | ((n & 15) << 1) | ((n >> 4) & 1);
}
__device__ __forceinline__ int iperm2(int k) {
  return (k & 0xE0) | ((k & 1) << 4) | ((k >> 1) & 15);
}
// A-storage: granule(row m, octet o) at byte o*256 + ((m ^ (o&3))&15)*16
__device__ __forceinline__ int aaddr(int m, int o) {
  return o * 256 + (((m ^ o) & 15) << 4);   // o&3 folded: m^o low bits (o<32, only low2 matter within &15 after ^ — (m^(o&3))&15 == ((m^o)&15) when o's bits>=2 ... NOT equal; use explicit:
}
__device__ __forceinline__ int aaddr2(int m, int o) {
  return o * 256 + (((m ^ (o & 3)) & 15) << 4);
}
// k_out A-tile swizzle (unchanged, independent)
__device__ __forceinline__ int aswz(int b) { return b ^ (((b >> 9) & 7) << 4); }

#define BAR() asm volatile("s_waitcnt lgkmcnt(0)\n\ts_barrier" ::: "memory")

// ---------- prep: T2g[v][perm2(h)] = f16( (emb[v]·W_ih[h] + b_ih[h] + b_hh[h]) * 2log2e )
//                  Wp[v][k'] = f16(W_ho[v][iperm2(k')])   (UNscaled, for k_out)
__global__ void k_prep(const float* __restrict__ emb, const float* __restrict__ W_ih,
                       const float* __restrict__ b_ih, const float* __restrict__ b_hh,
                       const float* __restrict__ W_ho,
                       _Float16* __restrict__ T2g, _Float16* __restrict__ Wp) {
  int bid = blockIdx.x, tid = threadIdx.x;
  if (bid < Vn) {
    int vv = bid, h = tid;
    const float4* e4 = (const float4*)(emb + vv * En);
    const float4* w4 = (const float4*)(W_ih + h * En);
    float acc = 0.f;
    #pragma unroll
    for (int i = 0; i < En / 4; ++i) {
      float4 a = e4[i], b = w4[i];
      acc += a.x * b.x + a.y * b.y + a.z * b.z + a.w * b.w;
    }
    T2g[vv * Hn + perm2(h)] = (_Float16)((acc + b_ih[h] + b_hh[h]) * LOG2E2);
  } else if (Wp) {
    int vv = bid - Vn, kp = tid;
    Wp[vv * Hn + kp] = (_Float16)W_ho[vv * Hn + iperm2(kp)];
  }
}

#define MF(ks) \
  acc0 = __builtin_amdgcn_mfma_f32_16x16x32_f16(af##ks, Bf[0][ks], acc0, 0, 0, 0); \
  acc1 = __builtin_amdgcn_mfma_f32_16x16x32_f16(af##ks, Bf[1][ks], acc1, 0, 0, 0);

// ---------- recurrence: 16 blocks x 512 thr (8 waves, 2/SIMD). Wave w: cols [32w,32w+32),
// full K=256. Fragment-order A layout: READS conflict-free by construction, WRITES 2-way
// (free). One lgkm-only barrier/step; exports fire-and-forget; RTN rounding.
__global__ __launch_bounds__(512, 1) void k_rnn(const int* __restrict__ inp,
    const float* __restrict__ hidden, const float* __restrict__ W_hh,
    const _Float16* __restrict__ T2g, float* out_base) {
  __shared__ _Float16 Abuf[2 * 16 * Hn];     // 16 KB  fragment-order, dbuf
  __shared__ unsigned char idxb[Sn * 16];    // 16 KB  [t][m]

  const int tid = threadIdx.x;
  const int l = tid & 63;
  const int w = tid >> 6;   // 0..7
  const int g = l >> 4;     // 0..3
  const int c = l & 15;
  const int bb0 = blockIdx.x << 4;

  // ---- stage idx bytes (V=128 fits u8); 512 thr x 8 = 16 rows x 256 int4
  #pragma unroll
  for (int i = 0; i < 8; ++i) {
    int gi = tid + (i << 9);
    int m = gi >> 8;
    int j = gi & 255;
    int4 d = ((const int4*)(inp + (size_t)(bb0 + m) * Sn))[j];
    int t0 = j << 2;
    idxb[(t0 + 0) * 16 + m] = (unsigned char)d.x;
    idxb[(t0 + 1) * 16 + m] = (unsigned char)d.y;
    idxb[(t0 + 2) * 16 + m] = (unsigned char)d.z;
    idxb[(t0 + 3) * 16 + m] = (unsigned char)d.w;
  }

  // ---- W_hh B-frags (pre-scaled): col n = 32w + 16cb2 + c, k via iperm2
  f16x8 Bf[2][8];
  #pragma unroll
  for (int cb2 = 0; cb2 < 2; ++cb2) {
    const float* wrow = W_hh + ((w << 5) + (cb2 << 4) + c) * Hn;
    #pragma unroll
    for (int ks = 0; ks < 8; ++ks) {
      union { _Float16 h[8]; f16x8 v8; } u;
      #pragma unroll
      for (int j = 0; j < 8; ++j)
        u.h[j] = (_Float16)(wrow[iperm2((ks << 5) + (g << 3) + j)] * LOG2E2);
      Bf[cb2][ks] = u.v8;
    }
  }

  // per-thread LDS byte offsets (loop-invariant)
  // read: chunk ks -> granule(row=c, o=4ks+g)
  int ard[8];
  #pragma unroll
  for (int ks = 0; ks < 8; ++ks) ard[ks] = aaddr2(c, (ks << 2) + g);
  // write: k'-pair {32w+2c,+1} -> o = 4w + (c>>2), word c&3; rows m = 4g+r
  int awr[4];
  #pragma unroll
  for (int r = 0; r < 4; ++r)
    awr[r] = aaddr2((g << 2) + r, (w << 2) + (c >> 2)) + ((c & 3) << 2);
  // x byte offset within a 512B T2g row: k'-pair bytes
  const int xoff = (w << 6) + (c << 2);

  // ---- initial h -> Abuf buffer 0
  #pragma unroll
  for (int r = 0; r < 4; ++r) {
    int m = (g << 2) + r;
    union { _Float16 h[2]; u32 q; } hp;
    hp.h[0] = (_Float16)hidden[(bb0 + m) * Hn + (w << 5) + c];        // cb2=0
    hp.h[1] = (_Float16)hidden[(bb0 + m) * Hn + (w << 5) + 16 + c];   // cb2=1
    *(u32*)((char*)Abuf + awr[r]) = hp.q;
  }

  // ---- x(0) gather from T2g (uniform base + u32 offset, 4B per lane)
  const char* T2b = (const char*)T2g;
  f16x2 xv[4];
  #pragma unroll
  for (int r = 0; r < 4; ++r) {
    u32 v0 = (u32)inp[(size_t)(bb0 + (g << 2) + r) * Sn];
    xv[r] = *(const f16x2*)(T2b + (v0 << 9) + xoff);
  }
  __syncthreads();

  char* outb = (char*)out_base;
  float* hfin = out_base + (size_t)Bn * Sn * Vn;

  // export u32 voffsets (byte), advanced by 512/step
  u32 vo[4];
  #pragma unroll
  for (int r = 0; r < 4; ++r)
    vo[r] = (u32)(((bb0 + (g << 2) + r) * Sn) * 512) + (u32)xoff;

  #pragma unroll 1
  for (int t = 0; t < Sn; ++t) {
    const int roff = (t & 1) << 13;
    const int woff = roff ^ 8192;

    // A-frag reads (conflict-free by construction)
    const char* ab = (const char*)Abuf + roff;
    f16x8 af0 = *(const f16x8*)(ab + ard[0]);
    f16x8 af1 = *(const f16x8*)(ab + ard[1]);
    f16x8 af2 = *(const f16x8*)(ab + ard[2]);
    f16x8 af3 = *(const f16x8*)(ab + ard[3]);
    f16x8 af4 = *(const f16x8*)(ab + ard[4]);
    f16x8 af5 = *(const f16x8*)(ab + ard[5]);
    f16x8 af6 = *(const f16x8*)(ab + ard[6]);
    f16x8 af7 = *(const f16x8*)(ab + ard[7]);

    // prefetch x(t+1): idx dword (DS) -> 4 x 4B gathers (VMEM, loads before stores)
    int tn = (t + 1 < Sn) ? t + 1 : t;
    u32 iv = *(const u32*)(idxb + tn * 16 + (g << 2));
    f16x2 xn[4];
    xn[0] = *(const f16x2*)(T2b + ((iv & 255u) << 9) + xoff);
    xn[1] = *(const f16x2*)(T2b + (((iv >> 8) & 255u) << 9) + xoff);
    xn[2] = *(const f16x2*)(T2b + (((iv >> 16) & 255u) << 9) + xoff);
    xn[3] = *(const f16x2*)(T2b + ((iv >> 24) << 9) + xoff);

    // acc init folds (pre-scaled) x
    f32x4 acc0 = { (float)xv[0][0], (float)xv[1][0], (float)xv[2][0], (float)xv[3][0] };
    f32x4 acc1 = { (float)xv[0][1], (float)xv[1][1], (float)xv[2][1], (float)xv[3][1] };

    MF(0) MF(1) MF(2) MF(3) MF(4) MF(5) MF(6) MF(7)

    // finalize: tanh = 1 - 2/(exp2(z')+1); RTN pack (unbiased)
    char* wb = (char*)Abuf + woff;
    #pragma unroll
    for (int r = 0; r < 4; ++r) {
      float e0 = __builtin_amdgcn_exp2f(acc0[r]);
      float e1 = __builtin_amdgcn_exp2f(acc1[r]);
      float h0 = fmaf(-2.f, __builtin_amdgcn_rcpf(e0 + 1.f), 1.f);
      float h1 = fmaf(-2.f, __builtin_amdgcn_rcpf(e1 + 1.f), 1.f);
      union { _Float16 h[2]; u32 q; } hp;
      hp.h[0] = (_Float16)h0;
      hp.h[1] = (_Float16)h1;
      *(u32*)(wb + awr[r]) = hp.q;           // LDS dbuf (b32, 2-way max)
      *(u32*)(outb + vo[r]) = hp.q;          // global export (no vmcnt wait)
      vo[r] += 512;
    }
    #pragma unroll
    for (int r = 0; r < 4; ++r) xv[r] = xn[r];

    BAR();   // lgkm drain only; exports stay in flight
  }

  // h_final from final LDS buffer (buffer 0 after t=1023)
  #pragma unroll
  for (int r = 0; r < 4; ++r) {
    int m = (g << 2) + r;
    union { _Float16 h[2]; u32 q; } hp;
    hp.q = *(const u32*)((const char*)Abuf + awr[r]);
    hfin[(bb0 + m) * Hn + (w << 5) + c]      = (float)hp.h[0];
    hfin[(bb0 + m) * Hn + (w << 5) + 16 + c] = (float)hp.h[1];
  }
}

// ---------- output GEMM: 4096 blocks x 512 thr (8 waves), in place over d_out.
template <int SLOW>
__global__ __launch_bounds__(512) void k_out(const float* __restrict__ W_ho,
    const float* __restrict__ b_ho, const _Float16* __restrict__ Wp,
    float* out_base) {
  __shared__ _Float16 At[64 * 256];                 // 32 KB, row-swizzled
  __shared__ _Float16 Wl[SLOW ? Vn * Hn : 8];       // 64 KB slow path only
  const int tid = threadIdx.x;
  const int l = tid & 63;
  const int w = tid >> 6;   // 0..7
  const int g = l >> 4;
  const int c = l & 15;
  const size_t m0 = (size_t)blockIdx.x << 6;
  const _Float16* hall = (const _Float16*)out_base;

  {
    const uint4* src = (const uint4*)(hall + (m0 << 8));
    #pragma unroll
    for (int i = 0; i < 4; ++i) {
      int gg = tid + (i << 9);
      int row = gg >> 5;
      int cb16 = (gg & 31) << 4;
      uint4 d = src[gg];
      *(uint4*)((char*)At + ((row * 512 + cb16) ^ ((row & 7) << 4))) = d;
    }
  }

  const int v = (w << 4) + c;
  f16x8 Bf[8];
  if (!SLOW) {
    const _Float16* wrow = Wp + v * Hn;
    #pragma unroll
    for (int ks = 0; ks < 8; ++ks)
      Bf[ks] = *(const f16x8*)(wrow + (ks << 5) + (g << 3));
    __syncthreads();
  } else {
    {
      int sv = tid >> 2;
      int kc = (tid & 3) << 6;
      const float* srcw = W_ho + sv * Hn + kc;
      for (int e = 0; e < 64; ++e) {
        int k = kc + e;
        *(_Float16*)((char*)Wl + ((sv * 512 + (perm2(k) << 1)) ^ ((sv & 7) << 4)))
            = (_Float16)srcw[e];
      }
    }
    __syncthreads();
    #pragma unroll
    for (int ks = 0; ks < 8; ++ks)
      Bf[ks] = *(const f16x8*)((const char*)Wl +
                 ((v * 512 + (ks << 6) + (g << 4)) ^ ((v & 7) << 4)));
  }
  const float bias = b_ho[v];

  #pragma unroll
  for (int mt = 0; mt < 4; ++mt) {
    f32x4 acc = {bias, bias, bias, bias};
    const int row = (mt << 4) + c;
    #pragma unroll
    for (int ks = 0; ks < 8; ++ks) {
      f16x8 a = *(const f16x8*)((const char*)At +
                  ((row * 512 + (ks << 6) + (g << 4)) ^ ((row & 7) << 4)));
      acc = __builtin_amdgcn_mfma_f32_16x16x32_f16(a, Bf[ks], acc, 0, 0, 0);
    }
    float* orow = out_base + (m0 + (mt << 4) + (g << 2)) * Vn + v;
    orow[0]      = acc[0];
    orow[Vn]     = acc[1];
    orow[2 * Vn] = acc[2];
    orow[3 * Vn] = acc[3];
  }
}

extern "C" void kernel_launch(void* const* d_in, const int* in_sizes, int n_in,
                              void* d_out, int out_size, void* d_ws, size_t ws_size,
                              hipStream_t stream) {
  (void)in_sizes; (void)n_in; (void)out_size;
  const int*   inp    = (const int*)  d_in[0];
  const float* hidden = (const float*)d_in[1];
  const float* emb    = (const float*)d_in[2];
  const float* W_ih   = (const float*)d_in[3];
  const float* b_ih   = (const float*)d_in[4];
  const float* W_hh   = (const float*)d_in[5];
  const float* b_hh   = (const float*)d_in[6];
  const float* W_ho   = (const float*)d_in[7];
  const float* b_ho   = (const float*)d_in[8];
  float* out = (float*)d_out;

  const bool useWs = (ws_size >= 131072);
  _Float16* T2g = useWs ? (_Float16*)d_ws
                        : (_Float16*)(out + (size_t)Bn * Sn * Vn);
  _Float16* Wp  = useWs ? (_Float16*)((char*)d_ws + 65536) : nullptr;

  k_prep<<<dim3(useWs ? 2 * Vn : Vn), dim3(Hn), 0, stream>>>(emb, W_ih, b_ih, b_hh,
                                                             W_ho, T2g, Wp);
  k_rnn<<<dim3(Bn / 16), dim3(512), 0, stream>>>(inp, hidden, W_hh, T2g, out);
  if (useWs)
    k_out<0><<<dim3((Bn * Sn) / 64), dim3(512), 0, stream>>>(W_ho, b_ho, Wp, out);
  else
    k_out<1><<<dim3((Bn * Sn) / 64), dim3(512), 0, stream>>>(W_ho, b_ho, nullptr, out);
}